// Round 6
// baseline (802.162 us; speedup 1.0000x reference)
//
#include <hip/hip_runtime.h>
#include <hip/hip_bf16.h>
#include <stdint.h>

#define T_TOK 2048
#define HD    2048
#define NE    16
#define FF    1024
#define TOPK  4
#define SHF   5632

typedef __attribute__((ext_vector_type(8))) short short8;
typedef __attribute__((ext_vector_type(4))) float f32x4;

typedef const __attribute__((address_space(1))) uint32_t* gp1_t;
typedef __attribute__((address_space(3))) uint32_t* lp3_t;

__device__ __forceinline__ void gload_lds16(const void* g, void* l) {
  __builtin_amdgcn_global_load_lds((gp1_t)g, (lp3_t)l, 16, 0, 0);
}

__device__ __forceinline__ unsigned short f2bf(float f) {
  __hip_bfloat16 h = __float2bfloat16(f);
  return __builtin_bit_cast(unsigned short, h);
}
__device__ __forceinline__ float bf2f(unsigned short u) {
  return __uint_as_float(((uint32_t)u) << 16);
}

// ---------------- prep: x -> bf16, zero d_out + counts ----------------
__global__ __launch_bounds__(256) void k_prep(const float* __restrict__ x,
                                              unsigned short* __restrict__ xb,
                                              float* __restrict__ out,
                                              int* __restrict__ counts, int n) {
  int i = blockIdx.x * blockDim.x + threadIdx.x;
  int stride = gridDim.x * blockDim.x;
  for (; i < n; i += stride) { xb[i] = f2bf(x[i]); out[i] = 0.f; }
  if (blockIdx.x == 0 && threadIdx.x < NE) counts[threadIdx.x] = 0;
}

// ---------------- weight transpose+cast: [b][K][N] fp32 -> [b][N][K] bf16 ------
__global__ __launch_bounds__(256) void k_transpose(const float* __restrict__ src,
    unsigned short* __restrict__ dst, int K, int N) {
  __shared__ unsigned short tile[64][72];
  const int k0 = blockIdx.x * 64;
  const int n0 = blockIdx.y * 64;
  const size_t boff = (size_t)blockIdx.z * K * N;
  src += boff; dst += boff;
  const int t = threadIdx.x;
  const int c4 = (t & 15) * 4;
  const int kr0 = (t >> 4) * 4;
#pragma unroll
  for (int j = 0; j < 4; ++j) {
    int kr = kr0 + j;
    float4 v = *(const float4*)(src + (size_t)(k0 + kr) * N + n0 + c4);
    tile[c4 + 0][kr] = f2bf(v.x);
    tile[c4 + 1][kr] = f2bf(v.y);
    tile[c4 + 2][kr] = f2bf(v.z);
    tile[c4 + 3][kr] = f2bf(v.w);
  }
  __syncthreads();
  const int nr = t >> 2;
  const int kc = (t & 3) * 8;
  unsigned short* orow = dst + (size_t)(n0 + nr) * K + k0;
  *(short8*)(orow + kc)      = *(const short8*)(&tile[nr][kc]);
  *(short8*)(orow + kc + 32) = *(const short8*)(&tile[nr][kc + 32]);
}

// ---------------- router -------------------------------------------------------
__global__ __launch_bounds__(64) void k_router(
    const float* __restrict__ x, const float* __restrict__ wr,
    const float* __restrict__ wsg, int* __restrict__ counts,
    int* __restrict__ list, float* __restrict__ wlist,
    float* __restrict__ gate_sh) {
  const int t = blockIdx.x;
  const int lane = threadIdx.x;
  const float* xrow = x + (size_t)t * HD;
  float p[NE + 1];
#pragma unroll
  for (int e = 0; e <= NE; ++e) p[e] = 0.f;
  for (int i = lane; i < HD; i += 64) {
    float xv = xrow[i];
    const float* wrow = wr + (size_t)i * NE;
#pragma unroll
    for (int e = 0; e < NE; ++e) p[e] += xv * wrow[e];
    p[NE] += xv * wsg[i];
  }
#pragma unroll
  for (int e = 0; e <= NE; ++e) {
    float v = p[e];
    for (int off = 32; off; off >>= 1) v += __shfl_xor(v, off);
    p[e] = v;
  }
  if (lane == 0) {
    gate_sh[t] = 1.f / (1.f + __expf(-p[NE]));
    float l[NE];
#pragma unroll
    for (int e = 0; e < NE; ++e) l[e] = p[e];
    int ids[TOPK]; float lg[TOPK];
#pragma unroll
    for (int k = 0; k < TOPK; ++k) {
      int best = 0; float bv = l[0];
#pragma unroll
      for (int e = 1; e < NE; ++e) { if (l[e] > bv) { bv = l[e]; best = e; } }
      ids[k] = best; lg[k] = bv; l[best] = -1e30f;
    }
    float m = lg[0], s = 0.f, w[TOPK];
#pragma unroll
    for (int k = 0; k < TOPK; ++k) { w[k] = __expf(lg[k] - m); s += w[k]; }
    float inv = 1.f / s;
#pragma unroll
    for (int k = 0; k < TOPK; ++k) {
      int e = ids[k];
      int pos = atomicAdd(&counts[e], 1);
      list[e * T_TOK + pos] = t;
      wlist[e * T_TOK + pos] = w[k] * inv;
    }
  }
}

// ---------------- offsets + weight compaction ----------------------------------
__global__ __launch_bounds__(256) void k_offsets(
    const int* __restrict__ counts, int* __restrict__ offsets,
    const float* __restrict__ wlist, float* __restrict__ wpair) {
  __shared__ int soff[NE];
  if (threadIdx.x == 0) {
    int off = 0;
    for (int e = 0; e < NE; ++e) { offsets[e] = off; soff[e] = off; off += counts[e]; }
    offsets[NE] = off;
  }
  __syncthreads();
  for (int idx = threadIdx.x; idx < NE * T_TOK; idx += 256) {
    int e = idx >> 11, pos = idx & (T_TOK - 1);
    if (pos < counts[e]) wpair[soff[e] + pos] = wlist[idx];
  }
}

// ---------------- 256x256x64 MFMA GEMM, 8 waves, m201-style 4-phase/K-tile -----
// 512 threads, LDS 2 x (A 256x64 + B 256x64) bf16 = 128 KB, 1 block/CU.
// Wave (wm,wn): rows {mh*128+wm*64..+64}, cols {nh*128+wn*32..+32} per (mh,nh).
// Per K-tile 4 phases: P0=Q(0,0) reads A-lo+B-lo, stage B-lo(t+1), vmcnt(4);
// P1=Q(0,1) reads B-hi, stage A-hi(t+1); P2=Q(1,1) reads A-hi, stage A-lo(t+2),
// vmcnt(4); P3=Q(1,0) re-reads B-lo, stage B-hi(t+2). ds_reads issued PRE-barrier.
// MODE 0: expert gate+up (A gathered; bf16 out) | 1: expert down (atomic f32)
// MODE 2: shared gate+up (bf16 out)             | 3: shared down splitK (atomic)
template<int MODE>
__global__ __launch_bounds__(512, 2) void k_gemm(
    const unsigned short* __restrict__ A, int lda, int nkt,
    const unsigned short* __restrict__ B0, const unsigned short* __restrict__ B1,
    int nsplit, size_t strideB, int ldb,
    unsigned short* __restrict__ O0, unsigned short* __restrict__ O1, int ldo,
    float* __restrict__ OF,
    const int* __restrict__ offsets, const int* __restrict__ counts,
    const int* __restrict__ list, const float* __restrict__ gate_sh)
{
  __shared__ unsigned short lds[2 * 32768];   // 128 KB
  __shared__ int tokLDS[256];

  const int cb = blockIdx.x, rb = blockIdx.y;
  const int e = (MODE <= 1) ? blockIdx.z : 0;
  const int kb0 = (MODE == 3) ? (int)blockIdx.z * (nkt * 64) : 0;
  const int tid = threadIdx.x, l = tid & 63, wid = tid >> 6;
  const int wm = wid >> 2, wn = wid & 3;

  int cnt = T_TOK;
  if (MODE <= 1) {
    cnt = counts[e];
    if (rb * 256 >= cnt) return;
  }
  if (MODE == 0) {
    if (tid < 256) {
      int r = rb * 256 + tid;
      tokLDS[tid] = list[e * T_TOK + (r < cnt ? r : cnt - 1)];
    }
    __syncthreads();
  }

  const unsigned short* Bsel = (cb < nsplit) ? B0 : B1;
  const int cb2 = (cb < nsplit) ? cb : cb - nsplit;
  const size_t eoff = (MODE <= 1) ? (size_t)e * strideB : (size_t)0;
  const unsigned short* Bbase = Bsel + eoff;

  uint32_t aOff[2][2], bOff[2][2];
#pragma unroll
  for (int h = 0; h < 2; ++h)
#pragma unroll
    for (int i = 0; i < 2; ++i) {
      int ridx = h * 128 + i * 64 + (tid >> 3);
      int arow;
      if (MODE == 0) arow = tokLDS[ridx];
      else if (MODE == 1) { int rr = rb * 256 + ridx; if (rr >= cnt) rr = cnt - 1; arow = offsets[e] + rr; }
      else arow = rb * 256 + ridx;
      uint32_t schunk = (uint32_t)((tid & 7) ^ (ridx & 7)) * 8u;
      aOff[h][i] = (uint32_t)arow * (uint32_t)lda + (uint32_t)kb0 + schunk;
      bOff[h][i] = (uint32_t)(cb2 * 256 + ridx) * (uint32_t)ldb + (uint32_t)kb0 + schunk;
    }

  auto SA = [&](int t, int h) {
    unsigned short* dst = lds + (t & 1) * 32768 + (h * 128 + wid * 8) * 64;
    gload_lds16(A + aOff[h][0] + t * 64, dst);
    gload_lds16(A + aOff[h][1] + t * 64, dst + 4096);
  };
  auto SB = [&](int t, int h) {
    unsigned short* dst = lds + (t & 1) * 32768 + 16384 + (h * 128 + wid * 8) * 64;
    gload_lds16(Bbase + bOff[h][0] + t * 64, dst);
    gload_lds16(Bbase + bOff[h][1] + t * 64, dst + 4096);
  };

  f32x4 acc[8][4];
#pragma unroll
  for (int mi = 0; mi < 8; ++mi)
#pragma unroll
    for (int ni = 0; ni < 4; ++ni) acc[mi][ni] = (f32x4){0.f, 0.f, 0.f, 0.f};

  const int rl = l & 15, kc4 = l >> 4;
  auto RA = [&](short8* dst, const char* lAb, int mh) {
#pragma unroll
    for (int mf = 0; mf < 4; ++mf)
#pragma unroll
      for (int kk = 0; kk < 2; ++kk) {
        int row = mh * 128 + wm * 64 + mf * 16 + rl;
        dst[mf * 2 + kk] = *(const short8*)(lAb + row * 128 + (((kk * 4 + kc4) ^ (row & 7)) * 16));
      }
  };
  auto RB = [&](short8* dst, const char* lBb, int nh) {
#pragma unroll
    for (int nf = 0; nf < 2; ++nf)
#pragma unroll
      for (int kk = 0; kk < 2; ++kk) {
        int col = nh * 128 + wn * 32 + nf * 16 + rl;
        dst[nf * 2 + kk] = *(const short8*)(lBb + col * 128 + (((kk * 4 + kc4) ^ (col & 7)) * 16));
      }
  };
  auto MM = [&](const short8* af, const short8* bf, int mh, int nh) {
    __builtin_amdgcn_s_setprio(1);
#pragma unroll
    for (int kk = 0; kk < 2; ++kk)
#pragma unroll
      for (int mf = 0; mf < 4; ++mf)
#pragma unroll
        for (int nf = 0; nf < 2; ++nf)
          acc[mh * 4 + mf][nh * 2 + nf] = __builtin_amdgcn_mfma_f32_16x16x32_bf16(
              af[mf * 2 + kk], bf[nf * 2 + kk], acc[mh * 4 + mf][nh * 2 + nf], 0, 0, 0);
    __builtin_amdgcn_s_setprio(0);
  };

  // prologue: A-lo0, B-hi0, B-lo0, A-hi0, A-lo1, B-hi1 (FIFO order matters)
  SA(0, 0); SB(0, 1); SB(0, 0); SA(0, 1); SA(1, 0); SB(1, 1);
  asm volatile("s_waitcnt vmcnt(4)" ::: "memory");
  __builtin_amdgcn_s_barrier();

  short8 af0[8], af1[8], bfL[4], bfH[4];
  for (int kt = 0; kt < nkt; ++kt) {
    const char* lAb = (const char*)(lds + (kt & 1) * 32768);
    const char* lBb = lAb + 32768;
    // ---- P0: read A-lo,B-lo; stage B-lo(kt+1); vmcnt; barrier; MFMA Q(0,0)
    asm volatile("" ::: "memory");
    RA(af0, lAb, 0); RB(bfL, lBb, 0);
    if (kt + 1 < nkt) SB(kt + 1, 0);
    if (kt + 2 < nkt) asm volatile("s_waitcnt vmcnt(4)" ::: "memory");
    else              asm volatile("s_waitcnt vmcnt(0)" ::: "memory");
    __builtin_amdgcn_s_barrier();
    asm volatile("" ::: "memory");
    MM(af0, bfL, 0, 0);
    asm volatile("" ::: "memory");
    __builtin_amdgcn_s_barrier();
    // ---- P1: read B-hi; stage A-hi(kt+1); barrier; MFMA Q(0,1)
    asm volatile("" ::: "memory");
    RB(bfH, lBb, 1);
    if (kt + 1 < nkt) SA(kt + 1, 1);
    asm volatile("" ::: "memory");
    __builtin_amdgcn_s_barrier();
    asm volatile("" ::: "memory");
    MM(af0, bfH, 0, 1);
    asm volatile("" ::: "memory");
    __builtin_amdgcn_s_barrier();
    // ---- P2: read A-hi; stage A-lo(kt+2); vmcnt; barrier; MFMA Q(1,1)
    asm volatile("" ::: "memory");
    RA(af1, lAb, 1);
    if (kt + 2 < nkt) SA(kt + 2, 0);
    if (kt + 2 < nkt) asm volatile("s_waitcnt vmcnt(4)" ::: "memory");
    else              asm volatile("s_waitcnt vmcnt(0)" ::: "memory");
    __builtin_amdgcn_s_barrier();
    asm volatile("" ::: "memory");
    MM(af1, bfH, 1, 1);
    asm volatile("" ::: "memory");
    __builtin_amdgcn_s_barrier();
    // ---- P3: re-read B-lo; stage B-hi(kt+2); barrier; MFMA Q(1,0)
    asm volatile("" ::: "memory");
    RB(bfL, lBb, 0);
    if (kt + 2 < nkt) SB(kt + 2, 1);
    asm volatile("" ::: "memory");
    __builtin_amdgcn_s_barrier();
    asm volatile("" ::: "memory");
    MM(af1, bfL, 1, 0);
    asm volatile("" ::: "memory");
    __builtin_amdgcn_s_barrier();
  }

  const int g4 = (l >> 4) * 4;
  const int cL = l & 15;

  if constexpr (MODE == 0 || MODE == 2) {
    unsigned short* Out = (cb < nsplit) ? O0 : O1;
    const int obase = (MODE == 0) ? offsets[e] : 0;
#pragma unroll
    for (int mh = 0; mh < 2; ++mh)
#pragma unroll
      for (int mf = 0; mf < 4; ++mf)
#pragma unroll
        for (int r = 0; r < 4; ++r) {
          int rloc = rb * 256 + mh * 128 + wm * 64 + mf * 16 + g4 + r;
          if (MODE == 0 && rloc >= cnt) continue;
          size_t orow = (size_t)(obase + rloc) * ldo + cb2 * 256;
#pragma unroll
          for (int nh = 0; nh < 2; ++nh)
#pragma unroll
            for (int nf = 0; nf < 2; ++nf)
              Out[orow + nh * 128 + wn * 32 + nf * 16 + cL] =
                  f2bf(acc[mh * 4 + mf][nh * 2 + nf][r]);
        }
  } else if constexpr (MODE == 1) {
#pragma unroll
    for (int mh = 0; mh < 2; ++mh)
#pragma unroll
      for (int mf = 0; mf < 4; ++mf)
#pragma unroll
        for (int r = 0; r < 4; ++r) {
          int rloc = rb * 256 + mh * 128 + wm * 64 + mf * 16 + g4 + r;
          if (rloc < cnt) {
            int tok = list[e * T_TOK + rloc];
            float* dst = OF + (size_t)tok * HD + cb2 * 256;
#pragma unroll
            for (int nh = 0; nh < 2; ++nh)
#pragma unroll
              for (int nf = 0; nf < 2; ++nf)
                atomicAdd(dst + nh * 128 + wn * 32 + nf * 16 + cL,
                          acc[mh * 4 + mf][nh * 2 + nf][r]);
          }
        }
  } else {
#pragma unroll
    for (int mh = 0; mh < 2; ++mh)
#pragma unroll
      for (int mf = 0; mf < 4; ++mf)
#pragma unroll
        for (int r = 0; r < 4; ++r) {
          int rloc = rb * 256 + mh * 128 + wm * 64 + mf * 16 + g4 + r;
          float g = gate_sh[rloc];
          float* dst = OF + (size_t)rloc * HD + cb2 * 256;
#pragma unroll
          for (int nh = 0; nh < 2; ++nh)
#pragma unroll
            for (int nf = 0; nf < 2; ++nf)
              atomicAdd(dst + nh * 128 + wn * 32 + nf * 16 + cL,
                        g * acc[mh * 4 + mf][nh * 2 + nf][r]);
        }
  }
}

// ---------------- fused SiLU(g)*u*(weight) elementwise, in place into g --------
__global__ __launch_bounds__(256) void k_silu(
    unsigned short* __restrict__ gq, const unsigned short* __restrict__ uq,
    const float* __restrict__ wrow, long total)
{
  long i = ((long)blockIdx.x * blockDim.x + threadIdx.x) * 4;
  const long stride = (long)gridDim.x * blockDim.x * 4;
  for (; i < total; i += stride) {
    ushort4 gv = *(const ushort4*)(gq + i);
    ushort4 uv = *(const ushort4*)(uq + i);
    float w = wrow ? wrow[i >> 10] : 1.f;
    float a0 = bf2f(gv.x), a1 = bf2f(gv.y), a2 = bf2f(gv.z), a3 = bf2f(gv.w);
    float b0 = bf2f(uv.x), b1 = bf2f(uv.y), b2 = bf2f(uv.z), b3 = bf2f(uv.w);
    ushort4 o;
    o.x = f2bf(a0 / (1.f + __expf(-a0)) * b0 * w);
    o.y = f2bf(a1 / (1.f + __expf(-a1)) * b1 * w);
    o.z = f2bf(a2 / (1.f + __expf(-a2)) * b2 * w);
    o.w = f2bf(a3 / (1.f + __expf(-a3)) * b3 * w);
    *(ushort4*)(gq + i) = o;
  }
}

extern "C" void kernel_launch(void* const* d_in, const int* in_sizes, int n_in,
                              void* d_out, int out_size, void* d_ws, size_t ws_size,
                              hipStream_t stream) {
  const float* x     = (const float*)d_in[0];
  const float* wrout = (const float*)d_in[1];
  const float* wgate = (const float*)d_in[2];
  const float* wup   = (const float*)d_in[3];
  const float* wdown = (const float*)d_in[4];
  const float* wsg   = (const float*)d_in[5];
  const float* wsu   = (const float*)d_in[6];
  const float* wsd   = (const float*)d_in[7];
  const float* wseg  = (const float*)d_in[8];
  float* out = (float*)d_out;

  char* ws = (char*)d_ws;
  unsigned short* xb = (unsigned short*)ws;                         // 8 MB
  char* region1 = ws + (size_t)(8u << 20);                          // 46 MB acts
  unsigned short* actg = (unsigned short*)region1;                  // 16 MB
  unsigned short* actu = (unsigned short*)(region1 + (size_t)(16u << 20));
  unsigned short* sgg  = (unsigned short*)region1;                  // 22 MB (reuse)
  unsigned short* sgu  = (unsigned short*)(region1 + (size_t)23068672);
  char* p3 = region1 + (size_t)46137344;                            // meta 1 MB
  int*   counts  = (int*)p3;
  int*   offsets = (int*)(p3 + 256);
  float* gateS   = (float*)(p3 + 512);
  float* wpair   = (float*)(p3 + 512 + 8192);
  int*   list    = (int*)(p3 + 512 + 8192 + 32768);
  float* wlist   = (float*)(p3 + 512 + 8192 + 32768 + 131072);
  char* p4 = p3 + (size_t)(1u << 20);
  unsigned short* W1 = (unsigned short*)p4;                         // 64 MB
  unsigned short* W2 = (unsigned short*)(p4 + (size_t)(64u << 20)); // 64 MB
  (void)ws_size; (void)in_sizes; (void)n_in; (void)out_size;

  const int n = T_TOK * HD;
  k_prep<<<dim3(4096), dim3(256), 0, stream>>>(x, xb, out, counts, n);
  k_router<<<dim3(T_TOK), dim3(64), 0, stream>>>(x, wrout, wseg, counts, list, wlist, gateS);
  k_offsets<<<dim3(1), dim3(256), 0, stream>>>(counts, offsets, wlist, wpair);

  // transpose+cast w_gate, w_up: [16][2048][1024] -> bf16 [16][1024][2048]
  k_transpose<<<dim3(32, 16, 16), dim3(256), 0, stream>>>(wgate, W1, HD, FF);
  k_transpose<<<dim3(32, 16, 16), dim3(256), 0, stream>>>(wup,   W2, HD, FF);

  // expert gate+up (separate panels): actg/actu [pairs,1024] bf16
  k_gemm<0><<<dim3(8, 8, 16), dim3(512), 0, stream>>>(
      xb, HD, 32, W1, W2, 4, (size_t)HD * FF, HD,
      actg, actu, FF, (float*)nullptr, offsets, counts, list, (const float*)nullptr);
  k_silu<<<dim3(4096), dim3(256), 0, stream>>>(actg, actu, wpair, (long)T_TOK * TOPK * FF);

  // transpose+cast w_down -> W1: [16][2048 n][1024 k]
  k_transpose<<<dim3(16, 32, 16), dim3(256), 0, stream>>>(wdown, W1, FF, HD);
  // expert down: out[tok] += act @ w_down[e]  (atomic f32)
  k_gemm<1><<<dim3(8, 8, 16), dim3(512), 0, stream>>>(
      actg, FF, 16, W1, W1, 1 << 30, (size_t)FF * HD, FF,
      (unsigned short*)nullptr, (unsigned short*)nullptr, HD,
      out, offsets, counts, list, (const float*)nullptr);

  // transpose+cast shared gate/up -> W2
  unsigned short* WsgT = W2;
  unsigned short* WsuT = W2 + (size_t)SHF * HD;
  k_transpose<<<dim3(32, 88, 1), dim3(256), 0, stream>>>(wsg, WsgT, HD, SHF);
  k_transpose<<<dim3(32, 88, 1), dim3(256), 0, stream>>>(wsu, WsuT, HD, SHF);

  // shared gate+up: sgg/sgu [2048,5632] bf16
  k_gemm<2><<<dim3(44, 8, 1), dim3(512), 0, stream>>>(
      xb, HD, 32, WsgT, WsuT, 22, (size_t)0, HD,
      sgg, sgu, SHF, (float*)nullptr, offsets, counts, list, (const float*)nullptr);
  k_silu<<<dim3(4096), dim3(256), 0, stream>>>(sgg, sgu, (const float*)nullptr, (long)T_TOK * SHF);

  // transpose+cast w_sh_down -> W1: [2048 n][5632 k]
  k_transpose<<<dim3(88, 32, 1), dim3(256), 0, stream>>>(wsd, W1, SHF, HD);
  // shared down, split-K=4: out += gate * (sg @ w_sh_down)  (atomic f32)
  k_gemm<3><<<dim3(8, 8, 4), dim3(512), 0, stream>>>(
      sgg, SHF, 22, W1, W1, 1 << 30, (size_t)0, SHF,
      (unsigned short*)nullptr, (unsigned short*)nullptr, HD,
      out, offsets, counts, list, gateS);
}

// Round 7
// 709.796 us; speedup vs baseline: 1.1301x; 1.1301x over previous
//
#include <hip/hip_runtime.h>
#include <hip/hip_bf16.h>
#include <stdint.h>

#define T_TOK 2048
#define HD    2048
#define NE    16
#define FF    1024
#define TOPK  4
#define SHF   5632

typedef __attribute__((ext_vector_type(8))) short short8;
typedef __attribute__((ext_vector_type(4))) float f32x4;

typedef const __attribute__((address_space(1))) uint32_t* gp1_t;
typedef __attribute__((address_space(3))) uint32_t* lp3_t;

__device__ __forceinline__ void gload_lds16(const void* g, void* l) {
  __builtin_amdgcn_global_load_lds((gp1_t)g, (lp3_t)l, 16, 0, 0);
}

__device__ __forceinline__ unsigned short f2bf(float f) {
  __hip_bfloat16 h = __float2bfloat16(f);
  return __builtin_bit_cast(unsigned short, h);
}
__device__ __forceinline__ float bf2f(unsigned short u) {
  return __uint_as_float(((uint32_t)u) << 16);
}

// ---------------- prep: x -> bf16, zero d_out + counts ----------------
__global__ __launch_bounds__(256) void k_prep(const float* __restrict__ x,
                                              unsigned short* __restrict__ xb,
                                              float* __restrict__ out,
                                              int* __restrict__ counts, int n) {
  int i = blockIdx.x * blockDim.x + threadIdx.x;
  int stride = gridDim.x * blockDim.x;
  for (; i < n; i += stride) { xb[i] = f2bf(x[i]); out[i] = 0.f; }
  if (blockIdx.x == 0 && threadIdx.x < NE) counts[threadIdx.x] = 0;
}

// ---------------- weight transpose+cast: [b][K][N] fp32 -> [b][N][K] bf16 ------
__global__ __launch_bounds__(256) void k_transpose(const float* __restrict__ src,
    unsigned short* __restrict__ dst, int K, int N) {
  __shared__ unsigned short tile[64][72];
  const int k0 = blockIdx.x * 64;
  const int n0 = blockIdx.y * 64;
  const size_t boff = (size_t)blockIdx.z * K * N;
  src += boff; dst += boff;
  const int t = threadIdx.x;
  const int c4 = (t & 15) * 4;
  const int kr0 = (t >> 4) * 4;
#pragma unroll
  for (int j = 0; j < 4; ++j) {
    int kr = kr0 + j;
    float4 v = *(const float4*)(src + (size_t)(k0 + kr) * N + n0 + c4);
    tile[c4 + 0][kr] = f2bf(v.x);
    tile[c4 + 1][kr] = f2bf(v.y);
    tile[c4 + 2][kr] = f2bf(v.z);
    tile[c4 + 3][kr] = f2bf(v.w);
  }
  __syncthreads();
  const int nr = t >> 2;
  const int kc = (t & 3) * 8;
  unsigned short* orow = dst + (size_t)(n0 + nr) * K + k0;
  *(short8*)(orow + kc)      = *(const short8*)(&tile[nr][kc]);
  *(short8*)(orow + kc + 32) = *(const short8*)(&tile[nr][kc + 32]);
}

// ---------------- router -------------------------------------------------------
__global__ __launch_bounds__(64) void k_router(
    const float* __restrict__ x, const float* __restrict__ wr,
    const float* __restrict__ wsg, int* __restrict__ counts,
    int* __restrict__ list, float* __restrict__ wlist,
    float* __restrict__ gate_sh) {
  const int t = blockIdx.x;
  const int lane = threadIdx.x;
  const float* xrow = x + (size_t)t * HD;
  float p[NE + 1];
#pragma unroll
  for (int e = 0; e <= NE; ++e) p[e] = 0.f;
  for (int i = lane; i < HD; i += 64) {
    float xv = xrow[i];
    const float* wrow = wr + (size_t)i * NE;
#pragma unroll
    for (int e = 0; e < NE; ++e) p[e] += xv * wrow[e];
    p[NE] += xv * wsg[i];
  }
#pragma unroll
  for (int e = 0; e <= NE; ++e) {
    float v = p[e];
    for (int off = 32; off; off >>= 1) v += __shfl_xor(v, off);
    p[e] = v;
  }
  if (lane == 0) {
    gate_sh[t] = 1.f / (1.f + __expf(-p[NE]));
    float l[NE];
#pragma unroll
    for (int e = 0; e < NE; ++e) l[e] = p[e];
    int ids[TOPK]; float lg[TOPK];
#pragma unroll
    for (int k = 0; k < TOPK; ++k) {
      int best = 0; float bv = l[0];
#pragma unroll
      for (int e = 1; e < NE; ++e) { if (l[e] > bv) { bv = l[e]; best = e; } }
      ids[k] = best; lg[k] = bv; l[best] = -1e30f;
    }
    float m = lg[0], s = 0.f, w[TOPK];
#pragma unroll
    for (int k = 0; k < TOPK; ++k) { w[k] = __expf(lg[k] - m); s += w[k]; }
    float inv = 1.f / s;
#pragma unroll
    for (int k = 0; k < TOPK; ++k) {
      int e = ids[k];
      int pos = atomicAdd(&counts[e], 1);
      list[e * T_TOK + pos] = t;
      wlist[e * T_TOK + pos] = w[k] * inv;
    }
  }
}

// ---------------- offsets + weight compaction ----------------------------------
__global__ __launch_bounds__(256) void k_offsets(
    const int* __restrict__ counts, int* __restrict__ offsets,
    const float* __restrict__ wlist, float* __restrict__ wpair) {
  __shared__ int soff[NE];
  if (threadIdx.x == 0) {
    int off = 0;
    for (int e = 0; e < NE; ++e) { offsets[e] = off; soff[e] = off; off += counts[e]; }
    offsets[NE] = off;
  }
  __syncthreads();
  for (int idx = threadIdx.x; idx < NE * T_TOK; idx += 256) {
    int e = idx >> 11, pos = idx & (T_TOK - 1);
    if (pos < counts[e]) wpair[soff[e] + pos] = wlist[idx];
  }
}

// ---------------- 128x128x64 MFMA GEMM, double-buffered 2-phase ---------------
// R1 core + minimum-2-phase pipeline: STAGE(kt+1) into other buffer BEFORE
// computing kt; counted vmcnt(8) (kt's loads retired, kt+1's stay in flight
// under the compute); raw s_barrier x2 per tile. 64 KB LDS -> 2 blocks/CU.
// grid: x = cb, y = rb, z = expert. 4 waves, wave tile 64x64.
// MODE 0: expert gate+up (A gathered by list; bf16 out at compact rows)
// MODE 1: expert down    (A compact rows; atomicAdd f32 -> OF[token])
// MODE 2: shared gate+up (A direct; bf16 out)
// MODE 3: shared down    (A direct; OF[t] += gate_sh[t]*acc, non-atomic RMW)
template<int MODE>
__global__ __launch_bounds__(256, 2) void k_gemm(
    const unsigned short* __restrict__ A, int lda, int nkt,
    const unsigned short* __restrict__ B0, const unsigned short* __restrict__ B1,
    int nsplit, size_t strideB, int ldb,
    unsigned short* __restrict__ O0, unsigned short* __restrict__ O1, int ldo,
    float* __restrict__ OF,
    const int* __restrict__ offsets, const int* __restrict__ counts,
    const int* __restrict__ list, const float* __restrict__ gate_sh)
{
  __shared__ unsigned short lds[2][2 * 8192];  // [buf][A 16KB | B 16KB]
  __shared__ int tokLDS[128];

  const int cb = blockIdx.x, rb = blockIdx.y;
  const int e = (MODE <= 1) ? blockIdx.z : 0;
  const int tid = threadIdx.x, l = tid & 63, wid = tid >> 6;
  const int wr = wid >> 1, wc = wid & 1;

  int cnt = T_TOK;
  if (MODE <= 1) {
    cnt = counts[e];
    if (rb * 128 >= cnt) return;
  }
  if (MODE == 0) {
    if (tid < 128) {
      int r = rb * 128 + tid;
      tokLDS[tid] = list[e * T_TOK + (r < cnt ? r : cnt - 1)];
    }
    __syncthreads();
  }

  const int swz8 = ((l & 7) ^ (l >> 3)) * 8;   // pre-swizzled source chunk (elems)
  const unsigned short* Bsel = (cb < nsplit) ? B0 : B1;
  const int cb2 = (cb < nsplit) ? cb : cb - nsplit;
  const size_t eoff = (MODE <= 1) ? (size_t)e * strideB : (size_t)0;

  const unsigned short* aS[4];
  const unsigned short* bS[4];
#pragma unroll
  for (int i = 0; i < 4; ++i) {
    int rloc = wid * 32 + i * 8 + (l >> 3);
    int arow;
    if (MODE == 0) arow = tokLDS[rloc];
    else if (MODE == 1) { int rr = rb * 128 + rloc; if (rr >= cnt) rr = cnt - 1; arow = offsets[e] + rr; }
    else arow = rb * 128 + rloc;
    aS[i] = A + (size_t)arow * lda + swz8;
    bS[i] = Bsel + eoff + (size_t)(cb2 * 128 + rloc) * ldb + swz8;
  }

  auto STAGE = [&](int kt) {
    unsigned short* base = &lds[kt & 1][0] + (wid * 32) * 64;
    const int k0 = kt * 64;
#pragma unroll
    for (int i = 0; i < 4; ++i) {
      gload_lds16(aS[i] + k0, base + i * 8 * 64);
      gload_lds16(bS[i] + k0, base + i * 8 * 64 + 8192);
    }
  };

  f32x4 acc[4][4];
#pragma unroll
  for (int mf = 0; mf < 4; ++mf)
#pragma unroll
    for (int nf = 0; nf < 4; ++nf) acc[mf][nf] = (f32x4){0.f, 0.f, 0.f, 0.f};

  STAGE(0);

  for (int kt = 0; kt < nkt; ++kt) {
    if (kt + 1 < nkt) {
      STAGE(kt + 1);                                   // other buffer; issued early
      asm volatile("s_waitcnt vmcnt(8)" ::: "memory"); // kt's 8 loads retired
    } else {
      asm volatile("s_waitcnt vmcnt(0)" ::: "memory");
    }
    __builtin_amdgcn_s_barrier();
    asm volatile("" ::: "memory");

    const char* lAb = (const char*)&lds[kt & 1][0];
    const char* lBb = lAb + 16384;
#pragma unroll
    for (int kk = 0; kk < 2; ++kk) {
      const int kb = kk * 64 + ((l >> 4) * 16);
      short8 af[4], bf[4];
#pragma unroll
      for (int mf = 0; mf < 4; ++mf) {
        int row = wr * 64 + mf * 16 + (l & 15);
        af[mf] = *(const short8*)(lAb + row * 128 + (kb ^ ((row & 7) << 4)));
      }
#pragma unroll
      for (int nf = 0; nf < 4; ++nf) {
        int n = wc * 64 + nf * 16 + (l & 15);
        bf[nf] = *(const short8*)(lBb + n * 128 + (kb ^ ((n & 7) << 4)));
      }
      __builtin_amdgcn_s_setprio(1);
#pragma unroll
      for (int mf = 0; mf < 4; ++mf)
#pragma unroll
        for (int nf = 0; nf < 4; ++nf)
          acc[mf][nf] = __builtin_amdgcn_mfma_f32_16x16x32_bf16(af[mf], bf[nf], acc[mf][nf], 0, 0, 0);
      __builtin_amdgcn_s_setprio(0);
    }
    asm volatile("" ::: "memory");
    __builtin_amdgcn_s_barrier();   // all reads of buf[kt&1] done before its restage
    asm volatile("" ::: "memory");
  }

  const int g4 = (l >> 4) * 4;
  const int cL = l & 15;
  const int colb = cb2 * 128 + wc * 64 + cL;

  if constexpr (MODE == 0) {
    unsigned short* Out = (cb < nsplit) ? O0 : O1;
    const int obase = offsets[e];
#pragma unroll
    for (int mf = 0; mf < 4; ++mf)
#pragma unroll
      for (int r = 0; r < 4; ++r) {
        int rloc = rb * 128 + wr * 64 + mf * 16 + g4 + r;
        if (rloc < cnt) {
          size_t orow = (size_t)(obase + rloc) * ldo + colb;
#pragma unroll
          for (int nf = 0; nf < 4; ++nf)
            Out[orow + nf * 16] = f2bf(acc[mf][nf][r]);
        }
      }
  } else if constexpr (MODE == 2) {
    unsigned short* Out = (cb < nsplit) ? O0 : O1;
#pragma unroll
    for (int mf = 0; mf < 4; ++mf)
#pragma unroll
      for (int r = 0; r < 4; ++r) {
        int rloc = rb * 128 + wr * 64 + mf * 16 + g4 + r;
        size_t orow = (size_t)rloc * ldo + colb;
#pragma unroll
        for (int nf = 0; nf < 4; ++nf)
          Out[orow + nf * 16] = f2bf(acc[mf][nf][r]);
      }
  } else if constexpr (MODE == 1) {
#pragma unroll
    for (int mf = 0; mf < 4; ++mf)
#pragma unroll
      for (int r = 0; r < 4; ++r) {
        int rloc = rb * 128 + wr * 64 + mf * 16 + g4 + r;
        if (rloc < cnt) {
          int tok = list[e * T_TOK + rloc];
          float* dst = OF + (size_t)tok * HD + colb;
#pragma unroll
          for (int nf = 0; nf < 4; ++nf)
            atomicAdd(dst + nf * 16, acc[mf][nf][r]);
        }
      }
  } else {
#pragma unroll
    for (int mf = 0; mf < 4; ++mf)
#pragma unroll
      for (int r = 0; r < 4; ++r) {
        int rloc = rb * 128 + wr * 64 + mf * 16 + g4 + r;
        float g = gate_sh[rloc];
        float* dst = OF + (size_t)rloc * HD + colb;
#pragma unroll
        for (int nf = 0; nf < 4; ++nf)
          dst[nf * 16] += g * acc[mf][nf][r];   // non-atomic RMW (expert atomics done)
      }
  }
}

// ---------------- fused SiLU(g)*u*(weight) elementwise, in place into g --------
__global__ __launch_bounds__(256) void k_silu(
    unsigned short* __restrict__ gq, const unsigned short* __restrict__ uq,
    const float* __restrict__ wrow, long total)
{
  long i = ((long)blockIdx.x * blockDim.x + threadIdx.x) * 4;
  const long stride = (long)gridDim.x * blockDim.x * 4;
  for (; i < total; i += stride) {
    ushort4 gv = *(const ushort4*)(gq + i);
    ushort4 uv = *(const ushort4*)(uq + i);
    float w = wrow ? wrow[i >> 10] : 1.f;
    float a0 = bf2f(gv.x), a1 = bf2f(gv.y), a2 = bf2f(gv.z), a3 = bf2f(gv.w);
    float b0 = bf2f(uv.x), b1 = bf2f(uv.y), b2 = bf2f(uv.z), b3 = bf2f(uv.w);
    ushort4 o;
    o.x = f2bf(a0 / (1.f + __expf(-a0)) * b0 * w);
    o.y = f2bf(a1 / (1.f + __expf(-a1)) * b1 * w);
    o.z = f2bf(a2 / (1.f + __expf(-a2)) * b2 * w);
    o.w = f2bf(a3 / (1.f + __expf(-a3)) * b3 * w);
    *(ushort4*)(gq + i) = o;
  }
}

extern "C" void kernel_launch(void* const* d_in, const int* in_sizes, int n_in,
                              void* d_out, int out_size, void* d_ws, size_t ws_size,
                              hipStream_t stream) {
  const float* x     = (const float*)d_in[0];
  const float* wrout = (const float*)d_in[1];
  const float* wgate = (const float*)d_in[2];
  const float* wup   = (const float*)d_in[3];
  const float* wdown = (const float*)d_in[4];
  const float* wsg   = (const float*)d_in[5];
  const float* wsu   = (const float*)d_in[6];
  const float* wsd   = (const float*)d_in[7];
  const float* wseg  = (const float*)d_in[8];
  float* out = (float*)d_out;

  char* ws = (char*)d_ws;
  unsigned short* xb = (unsigned short*)ws;                         // 8 MB
  char* region1 = ws + (size_t)(8u << 20);                          // 46 MB acts
  unsigned short* actg = (unsigned short*)region1;                  // 16 MB
  unsigned short* actu = (unsigned short*)(region1 + (size_t)(16u << 20));
  unsigned short* sgg  = (unsigned short*)region1;                  // 22 MB (reuse)
  unsigned short* sgu  = (unsigned short*)(region1 + (size_t)23068672);
  char* p3 = region1 + (size_t)46137344;                            // meta 1 MB
  int*   counts  = (int*)p3;
  int*   offsets = (int*)(p3 + 256);
  float* gateS   = (float*)(p3 + 512);
  float* wpair   = (float*)(p3 + 512 + 8192);
  int*   list    = (int*)(p3 + 512 + 8192 + 32768);
  float* wlist   = (float*)(p3 + 512 + 8192 + 32768 + 131072);
  char* p4 = p3 + (size_t)(1u << 20);
  unsigned short* W1 = (unsigned short*)p4;                         // 64 MB
  unsigned short* W2 = (unsigned short*)(p4 + (size_t)(64u << 20)); // 64 MB
  (void)ws_size; (void)in_sizes; (void)n_in; (void)out_size;

  const int n = T_TOK * HD;
  k_prep<<<dim3(4096), dim3(256), 0, stream>>>(x, xb, out, counts, n);
  k_router<<<dim3(T_TOK), dim3(64), 0, stream>>>(x, wrout, wseg, counts, list, wlist, gateS);
  k_offsets<<<dim3(1), dim3(256), 0, stream>>>(counts, offsets, wlist, wpair);

  // transpose+cast w_gate, w_up: [16][2048][1024] -> bf16 [16][1024][2048]
  k_transpose<<<dim3(32, 16, 16), dim3(256), 0, stream>>>(wgate, W1, HD, FF);
  k_transpose<<<dim3(32, 16, 16), dim3(256), 0, stream>>>(wup,   W2, HD, FF);

  // expert gate+up: actg/actu [pairs,1024] bf16
  k_gemm<0><<<dim3(16, 16, 16), dim3(256), 0, stream>>>(
      xb, HD, 32, W1, W2, 8, (size_t)HD * FF, HD,
      actg, actu, FF, (float*)nullptr, offsets, counts, list, (const float*)nullptr);
  k_silu<<<dim3(4096), dim3(256), 0, stream>>>(actg, actu, wpair, (long)T_TOK * TOPK * FF);

  // transpose+cast w_down -> W1: [16][2048 n][1024 k]
  k_transpose<<<dim3(16, 32, 16), dim3(256), 0, stream>>>(wdown, W1, FF, HD);
  // expert down: out[tok] += act @ w_down[e]  (atomic f32)
  k_gemm<1><<<dim3(16, 16, 16), dim3(256), 0, stream>>>(
      actg, FF, 16, W1, W1, 1 << 30, (size_t)FF * HD, FF,
      (unsigned short*)nullptr, (unsigned short*)nullptr, HD,
      out, offsets, counts, list, (const float*)nullptr);

  // transpose+cast shared gate/up -> W2
  unsigned short* WsgT = W2;
  unsigned short* WsuT = W2 + (size_t)SHF * HD;
  k_transpose<<<dim3(32, 88, 1), dim3(256), 0, stream>>>(wsg, WsgT, HD, SHF);
  k_transpose<<<dim3(32, 88, 1), dim3(256), 0, stream>>>(wsu, WsuT, HD, SHF);

  // shared gate+up: sgg/sgu [2048,5632] bf16
  k_gemm<2><<<dim3(88, 16, 1), dim3(256), 0, stream>>>(
      xb, HD, 32, WsgT, WsuT, 44, (size_t)0, HD,
      sgg, sgu, SHF, (float*)nullptr, offsets, counts, list, (const float*)nullptr);
  k_silu<<<dim3(4096), dim3(256), 0, stream>>>(sgg, sgu, (const float*)nullptr, (long)T_TOK * SHF);

  // transpose+cast w_sh_down -> W1: [2048 n][5632 k]
  k_transpose<<<dim3(88, 32, 1), dim3(256), 0, stream>>>(wsd, W1, SHF, HD);
  // shared down: out[t] += gate[t] * (sg @ w_sh_down)  (non-atomic RMW)
  k_gemm<3><<<dim3(16, 16, 1), dim3(256), 0, stream>>>(
      sgg, SHF, 88, W1, W1, 1 << 30, (size_t)0, SHF,
      (unsigned short*)nullptr, (unsigned short*)nullptr, HD,
      out, offsets, counts, list, gateS);
}